// Round 5
// baseline (560.463 us; speedup 1.0000x reference)
//
#include <hip/hip_runtime.h>

// MultiHead_Attn: B=8, S=1024, E=512, H=8.  fp32 I/O, fp16 MFMA internal.
//
// Reshape semantics (R3-verified): head (b,h) of (x@W^T).view(b,8,1024,512) is
// a CONTIGUOUS 1024x512 chunk of the natural row-major proj output.  Wo folded
// in early:  VWo_t[z][eo][s'] = Wo_h @ V_z^T,  out += P_z @ VWo_t_z^T.
// Group g = heads [g*HG,(g+1)*HG) of ALL 8 batches; in16 = [tensor][b][HG*128][512].
//
// R13 = R12 with the B-read double-offset bug fixed (Bs=As+4096 AND bBase
// included +4096 -> B frags read the other ring buffer mid-staging -> NaN).
// R12 design (unchanged): proj/vwo/energy on 128x256-tile 4-wave core,
// 2 blocks/CU:
//   - TLP overlap (m114): two independent desynced blocks per CU -> one
//     block's LDS-read burst overlaps the other's MFMA burst.  (R9-R11
//     lockstep 8-wave choreography pinned MfmaUtil at ~30%.)
//   - ONE barrier per K-tile (ring-2 buffer swap); compiler's fine-grained
//     lgkmcnt waits handle read->MFMA ordering (m97: near-optimal)
//   - 48KB LDS ring + acc 128 VGPR + __launch_bounds__(256,2) -> 2 blocks/CU
//   - paired-row XOR LDS layout (R11-verified: SQ_LDS_BANK_CONFLICT = 0)
//   - XCD-chunked blockIdx swizzle on proj (A-panel L2 locality, bijective)
// pv (k-limited, atomic epilogue) kept on the 128^2 legacy core.
// VWo and energy remain SEPARATE dispatches: Vp is overlaid on E.
//
// Scratch (fp16 el): W16 8.39M | in16 3*HG*524288 | Qp,Kp,VWo zc*524288
// | E zc*1048576 (Vp overlay).  HG=4: 188 MiB, HG=2: 102 MiB, HG=1: 59 MiB.

typedef _Float16 half8 __attribute__((ext_vector_type(8)));
typedef _Float16 half4v __attribute__((ext_vector_type(4)));
typedef float f32x4 __attribute__((ext_vector_type(4)));

typedef __attribute__((address_space(3))) unsigned int lds_u32_t;
typedef __attribute__((address_space(1))) unsigned int g_u32_t;

__device__ __forceinline__ void glds16(const void* g, void* l) {
  // 16B/lane, LDS dest = wave-uniform base + lane*16  [m97: 517->874 TF]
  __builtin_amdgcn_global_load_lds((const g_u32_t*)g, (lds_u32_t*)l, 16, 0, 0);
}

// ========================= 128x256 4-wave core ==============================
// Tile M=128 (A rows) x N=256 (B rows) x BK=32.  Waves 2Mx2N, each 64x128
// (acc[4][8] = 128 VGPR).  LDS ring-2: buf = [A 4096 el][B 8192 el], 48KB.
// Paired-row layout (R11-verified conflict-free): LDS row' (128B) holds
// global rows {2r',2r'+1}; seg s' = ((g&1)*4 + c) ^ (r'&7); c = k-chunk(8el).
template <int NT>
__device__ __forceinline__ void gemm128x256_core(const _Float16* __restrict__ A,
                                                 const _Float16* __restrict__ B,
                                                 int lda, int ldb,
                                                 _Float16* smem, f32x4 (&acc)[4][8]) {
  int tid = (int)threadIdx.x;
  int w = tid >> 6, lane = tid & 63;
  int wr2 = (w >> 1) * 32;   // (wr = (w>>1)*64)/2  LDS-row base, A
  int wc2 = (w & 1) * 64;    // (wc = (w&1)*128)/2  LDS-row base, B
  int lr = lane & 15, hi = lane >> 4;
  // read swizzle: s' = ((g&1)*4 + hi) ^ (row'&7); g&1 = lane&1, row'&7=(lr>>1)&7
  int sp = ((((lane & 1) << 2) + hi) ^ ((lr >> 1) & 7)) << 3;  // elements
  int aBase = (wr2 + (lr >> 1)) * 64 + sp;
  int bBase = 4096 + (wc2 + (lr >> 1)) * 64 + sp;  // +4096 = B panel offset
  // NOTE: B frags are read via As[bBase + ...] -- the panel offset lives ONLY
  // in bBase (R12 bug: also added it to the pointer -> OOB -> NaN).

  // staging per-lane source offsets (elements); A: 2 glds, B: 4 glds
  int srcA[2], srcB[4], dstA[2], dstB[4];
#pragma unroll
  for (int e = 0; e < 2; e++) {
    int X = e * 4096 + tid * 16;        // dest byte in 8KB A panel
    int rp = X >> 7;
    int s = ((X >> 4) & 7) ^ (rp & 7);
    srcA[e] = (2 * rp + (s >> 2)) * lda + ((s & 3) << 3);
    dstA[e] = e * 2048 + w * 512;       // wave-uniform el (+ lane*16B by HW)
  }
#pragma unroll
  for (int e = 0; e < 4; e++) {
    int X = e * 4096 + tid * 16;        // dest byte in 16KB B panel
    int rp = X >> 7;
    int s = ((X >> 4) & 7) ^ (rp & 7);
    srcB[e] = (2 * rp + (s >> 2)) * ldb + ((s & 3) << 3);
    dstB[e] = 4096 + e * 2048 + w * 512;
  }

  // prologue: stage tile 0 -> buf0
#pragma unroll
  for (int e = 0; e < 2; e++) glds16(A + srcA[e], smem + dstA[e]);
#pragma unroll
  for (int e = 0; e < 4; e++) glds16(B + srcB[e], smem + dstB[e]);

#pragma unroll
  for (int t = 0; t < NT; t++) {
    // single barrier per tile: buf[t&1] staged+visible (own vmcnt drained by
    // syncthreads); all waves' reads of buf[(t+1)&1] (tile t-1) retired.
    __syncthreads();
    const _Float16* As = smem + (t & 1) * 12288;
    half8 a[4], b[4], c[4];
#pragma unroll
    for (int ni = 0; ni < 4; ni++) b[ni] = *(const half8*)&As[bBase + ni * 512];
#pragma unroll
    for (int mi = 0; mi < 4; mi++) a[mi] = *(const half8*)&As[aBase + mi * 512];
    if (t + 1 < NT) {
      _Float16* nb = smem + ((t + 1) & 1) * 12288;
#pragma unroll
      for (int e = 0; e < 2; e++) glds16(A + srcA[e] + (t + 1) * 32, nb + dstA[e]);
#pragma unroll
      for (int e = 0; e < 4; e++) glds16(B + srcB[e] + (t + 1) * 32, nb + dstB[e]);
    }
    __builtin_amdgcn_sched_barrier(0);  // pin group-1 reads + prefetch issue
#pragma unroll
    for (int ni = 0; ni < 4; ni++)
      c[ni] = *(const half8*)&As[bBase + (ni + 4) * 512];  // group-2 B frags
    __builtin_amdgcn_s_setprio(1);
    // compiler inserts fine lgkmcnt waits; group-2 reads overlap group-1 MFMA
#pragma unroll
    for (int mi = 0; mi < 4; mi++)
#pragma unroll
      for (int ni = 0; ni < 4; ni++)
        acc[mi][ni] = __builtin_amdgcn_mfma_f32_16x16x32_f16(a[mi], b[ni],
                                                             acc[mi][ni], 0, 0, 0);
#pragma unroll
    for (int mi = 0; mi < 4; mi++)
#pragma unroll
      for (int ni = 0; ni < 4; ni++)
        acc[mi][ni + 4] = __builtin_amdgcn_mfma_f32_16x16x32_f16(a[mi], c[ni],
                                                                 acc[mi][ni + 4], 0, 0, 0);
    __builtin_amdgcn_s_setprio(0);
  }
  __syncthreads();  // all K-loop reads retired -> LDS free for epilogue reuse
}

// fp16 epilogue: per-wave private 64x64 LDS region x2 rounds (ni 0-3 / 4-7),
// XOR-swizzled segs, 16B coalesced stores.  Reuses staging LDS.
__device__ __forceinline__ void epilogue128x256(f32x4 (&acc)[4][8], _Float16* lds,
                                                _Float16* Cp, size_t cOff,
                                                int i0, int j0, int ldc) {
  int tid = (int)threadIdx.x;
  int w = tid >> 6, lane = tid & 63;
  int wr = (w >> 1) * 64, wc = (w & 1) * 128;
  int r0 = (lane >> 4) * 4, cl = lane & 15;
  _Float16* T = lds + w * 4096;
#pragma unroll
  for (int h = 0; h < 2; h++) {
#pragma unroll
    for (int mi = 0; mi < 4; mi++)
#pragma unroll
      for (int ni = 0; ni < 4; ni++) {
        int colb = ni * 16 + cl;
#pragma unroll
        for (int r = 0; r < 4; r++) {
          int row = mi * 16 + r0 + r;  // 0..63
          T[row * 64 + ((((colb >> 3) ^ row) & 7) << 3) + (colb & 7)] =
              (_Float16)acc[mi][h * 4 + ni][r];
        }
      }
    // wave-private region; same-wave LDS ops are in-order
#pragma unroll
    for (int st = 0; st < 8; st++) {
      int row = st * 8 + (lane >> 3);
      int c8 = lane & 7;
      half8 hh = *(const half8*)&T[row * 64 + (((c8 ^ row) & 7) << 3)];
      *(half8*)(Cp + cOff + (size_t)(i0 + wr + row) * ldc + j0 + wc + h * 64 + c8 * 8) = hh;
    }
  }
}

// ---- QKV projection: M=HG*1024, N=4096, K=512 ------------------------------
template <int HG>
__global__ __launch_bounds__(256, 2) void proj256(const _Float16* __restrict__ in16,
                                                  const _Float16* __restrict__ W16,
                                                  _Float16* __restrict__ Qp,
                                                  _Float16* __restrict__ Kp,
                                                  _Float16* __restrict__ Vp) {
  __shared__ __align__(16) _Float16 smem[24576];
  int x = (int)blockIdx.x, Y = (int)blockIdx.y;
  // XCD-chunked swizzle: grid.x = HG*128 (div by 8); XCD k gets contiguous
  // work chunk -> co-XCD blocks share A panels (L2 locality).
  int work = (x & 7) * (HG * 16) + (x >> 3);
  int it = work >> 4, jt = work & 15;
  const _Float16* A = in16 + (size_t)Y * HG * 524288 + (size_t)it * 65536;
  const _Float16* B = W16 + (size_t)Y * 2097152 + (size_t)jt * 131072;
  _Float16* C = (Y == 0 ? Qp : (Y == 1 ? Kp : Vp));
  f32x4 acc[4][8] = {};
  gemm128x256_core<16>(A, B, 512, 512, smem, acc);
  epilogue128x256(acc, smem, C, 0, it * 128, jt * 256, 4096);
}

// ---- VWo: VWo_t[z][eo][s'] = Wo_h @ V_z^T  (reads Vp = E overlay!) ---------
template <int HG>
__global__ __launch_bounds__(256, 2) void vwo256(const _Float16* __restrict__ Vp,
                                                 const _Float16* __restrict__ WoG,
                                                 _Float16* __restrict__ VWo) {
  __shared__ __align__(16) _Float16 smem[24576];
  int x = (int)blockIdx.x, Y = (int)blockIdx.y, Z = (int)blockIdx.z;
  size_t z = (size_t)Z * HG + Y;
  int i0 = (x >> 2) * 128, j0 = (x & 3) * 256;  // i0: eo-tile, j0: s'-tile
  const _Float16* A = WoG + (size_t)Y * 512 + (size_t)i0 * 4096;
  const _Float16* B = Vp + z * 524288 + (size_t)j0 * 512;
  f32x4 acc[4][8] = {};
  gemm128x256_core<16>(A, B, 4096, 512, smem, acc);
  epilogue128x256(acc, smem, VWo, z * 524288, i0, j0, 1024);
}

// ---- energy: E_z = Qp_z @ Kp_z^T, causal grid (20 of 32 tiles) -------------
template <int HG>
__global__ __launch_bounds__(256, 2) void energy256(const _Float16* __restrict__ Qp,
                                                    const _Float16* __restrict__ Kp,
                                                    _Float16* __restrict__ E) {
  __shared__ __align__(16) _Float16 smem[24576];
  int x = (int)blockIdx.x, Y = (int)blockIdx.y, Z = (int)blockIdx.z;
  size_t z = (size_t)Z * HG + Y;
  // tile (ti,tj) valid iff 2*tj <= ti: tj=0:ti0-7, 1:2-7, 2:4-7, 3:6-7
  int ti, tj;
  if (x < 8)       { tj = 0; ti = x; }
  else if (x < 14) { tj = 1; ti = x - 6; }
  else if (x < 18) { tj = 2; ti = x - 10; }
  else             { tj = 3; ti = x - 12; }
  int i0 = ti * 128, j0 = tj * 256;
  const _Float16* A = Qp + z * 524288 + (size_t)i0 * 512;
  const _Float16* B = Kp + z * 524288 + (size_t)j0 * 512;
  f32x4 acc[4][8] = {};
  gemm128x256_core<16>(A, B, 512, 512, smem, acc);
  epilogue128x256(acc, smem, E, z * 1048576, i0, j0, 1024);
}

// ===================== legacy 128^2 core (pv only) ==========================
template <int HL>
__device__ __forceinline__ void gemm_core(const _Float16* A, const _Float16* B,
                                          int lda, int ldb, int kmax,
                                          long sAh, long sBh,
                                          _Float16* As, _Float16* Bs,
                                          f32x4 (&acc)[4][4]) {
  int tid = (int)threadIdx.x;
  int w = tid >> 6, lane = tid & 63;
  int wr = (w >> 1) * 64, wc = (w & 1) * 64;
  int lr = lane & 15, lk = (lane >> 4) * 8;
  int srow = lane >> 2, sseg = (lane & 3) * 8;  // staging lane map

  for (int h = 0; h < HL; h++) {
    const _Float16* Ah = A + (size_t)h * sAh;
    const _Float16* Bh = B + (size_t)h * sBh;
    for (int k0 = 0; k0 < kmax; k0 += 64) {
      __syncthreads();  // previous iteration's frag reads complete
#pragma unroll
      for (int p = 0; p < 2; p++)
#pragma unroll
        for (int t = 0; t < 2; t++) {
          glds16(Ah + (size_t)(w * 32 + t * 16 + srow) * lda + k0 + p * 32 + sseg,
                 As + p * 4096 + (w * 32 + t * 16) * 32);
          glds16(Bh + (size_t)(w * 32 + t * 16 + srow) * ldb + k0 + p * 32 + sseg,
                 Bs + p * 4096 + (w * 32 + t * 16) * 32);
        }
      __syncthreads();  // vmcnt drained by barrier -> panels visible
#pragma unroll
      for (int p = 0; p < 2; p++) {
        half8 a[4], b[4];
#pragma unroll
        for (int mi = 0; mi < 4; mi++)
          a[mi] = *(half8*)&As[p * 4096 + (wr + mi * 16 + lr) * 32 + lk];
#pragma unroll
        for (int ni = 0; ni < 4; ni++)
          b[ni] = *(half8*)&Bs[p * 4096 + (wc + ni * 16 + lr) * 32 + lk];
#pragma unroll
        for (int mi = 0; mi < 4; mi++)
#pragma unroll
          for (int ni = 0; ni < 4; ni++)
            acc[mi][ni] =
                __builtin_amdgcn_mfma_f32_16x16x32_f16(a[mi], b[ni], acc[mi][ni], 0, 0, 0);
      }
    }
  }
}

// ---- atomic f32 epilogue (PV accumulation over heads) ----------------------
__device__ __forceinline__ void epilogue_atomic(f32x4 (&acc)[4][4], float* Cp,
                                                size_t cOff, int i0, int j0, int ldc) {
  int tid = (int)threadIdx.x;
  int w = tid >> 6, lane = tid & 63;
  int wr = (w >> 1) * 64, wc = (w & 1) * 64;
  int r0 = (lane >> 4) * 4, col = lane & 15;
#pragma unroll
  for (int mi = 0; mi < 4; mi++)
#pragma unroll
    for (int ni = 0; ni < 4; ni++)
#pragma unroll
      for (int r = 0; r < 4; r++)
        unsafeAtomicAdd(Cp + cOff + (size_t)(i0 + wr + mi * 16 + r0 + r) * ldc +
                            j0 + wc + ni * 16 + col,
                        acc[mi][ni][r]);
}

// ---- PV: out += P_z @ VWo_t_z^T (k-limited, HL heads in-register) ----------
template <int HG, int HL>
__global__ __launch_bounds__(256) void pv_kernel(const _Float16* __restrict__ E,
                                                 const _Float16* __restrict__ VWo,
                                                 float* __restrict__ out) {
  __shared__ __align__(16) _Float16 smem[17408];
  int x = (int)blockIdx.x, Y = (int)blockIdx.y, Z = (int)blockIdx.z;
  int i0 = (x >> 2) * 128, j0 = (x & 3) * 128;
  int kmax = i0 + 128;  // causal: P[q][s']==0 for s'>q
  const _Float16* A = E + ((size_t)Z * HG + (size_t)Y * HL) * 1048576 + (size_t)i0 * 1024;
  const _Float16* B = VWo + ((size_t)Z * HG + (size_t)Y * HL) * 524288 + (size_t)j0 * 1024;
  f32x4 acc[4][4] = {};
  gemm_core<HL>(A, B, 1024, 1024, kmax, 1048576, 524288, smem, smem + 8192, acc);
  epilogue_atomic(acc, out, (size_t)Z * 524288, i0, j0, 512);
}

// ---- row softmax, in-place E -> P (fp16), trimmed to valid 256-chunks ------
__global__ __launch_bounds__(256) void softmax_rows(void* __restrict__ Ep) {
  int R = (int)blockIdx.x * 4 + ((int)threadIdx.x >> 6);
  int lane = (int)threadIdx.x & 63;
  int i = R & 1023;
  int nt = (i >> 8) + 1;
  _Float16* row = (_Float16*)Ep + (size_t)R * 1024;
  float x[16];
  float m = -3.0e38f;
#pragma unroll
  for (int t = 0; t < 4; t++) {
    if (t < nt) {  // wave-uniform
      int j0 = t * 256 + lane * 4;
      half4v h = *(const half4v*)(row + j0);
#pragma unroll
      for (int c = 0; c < 4; c++) {
        float v = (j0 + c <= i) ? (float)h[c] * 0.125f : -3.0e38f;
        x[t * 4 + c] = v;
        m = fmaxf(m, v);
      }
    }
  }
#pragma unroll
  for (int s = 32; s > 0; s >>= 1) m = fmaxf(m, __shfl_xor(m, s, 64));
  float p[16];
  float sum = 0.0f;
#pragma unroll
  for (int t = 0; t < 4; t++) {
    if (t < nt) {
#pragma unroll
      for (int c = 0; c < 4; c++) {
        p[t * 4 + c] = exp2f((x[t * 4 + c] - m) * 1.44269504f);
        sum += p[t * 4 + c];
      }
    }
  }
#pragma unroll
  for (int s = 32; s > 0; s >>= 1) sum += __shfl_xor(sum, s, 64);
  float inv = 1.0f / sum;
#pragma unroll
  for (int t = 0; t < 4; t++) {
    if (t < nt) {
      int j0 = t * 256 + lane * 4;
      half4v h;
#pragma unroll
      for (int c = 0; c < 4; c++) h[c] = (_Float16)(p[t * 4 + c] * inv);
      *(half4v*)(row + j0) = h;
    }
  }
}

// ---- merged weight preconvert + bias init ----------------------------------
__global__ __launch_bounds__(256) void wbconv(const float* __restrict__ Wq,
                                              const float* __restrict__ Wk,
                                              const float* __restrict__ Wv,
                                              const float* __restrict__ Wo,
                                              _Float16* __restrict__ W16,
                                              float* __restrict__ out,
                                              const float* __restrict__ bo) {
  int bx = (int)blockIdx.x;
  if (bx < 4096) {
    size_t base = ((size_t)bx * 256 + threadIdx.x) * 8;
    int wid = (int)(base >> 21);
    size_t off = base & 2097151;
    const float* src = wid == 0 ? Wq : (wid == 1 ? Wk : (wid == 2 ? Wv : Wo));
    float4 a = *(const float4*)(src + off);
    float4 b = *(const float4*)(src + off + 4);
    half8 h;
    h[0] = (_Float16)a.x; h[1] = (_Float16)a.y; h[2] = (_Float16)a.z; h[3] = (_Float16)a.w;
    h[4] = (_Float16)b.x; h[5] = (_Float16)b.y; h[6] = (_Float16)b.z; h[7] = (_Float16)b.w;
    *(half8*)(W16 + base) = h;
  } else {
    size_t idx = ((size_t)(bx - 4096) * 256 + threadIdx.x) * 4;
    *(float4*)(out + idx) = *(const float4*)(bo + (idx & 511));
  }
}

// ---- input group-slice preconvert: in16[tensor][b][HG*128*512] fp16 --------
template <int HG>
__global__ __launch_bounds__(256) void inconv(const float* __restrict__ q,
                                              const float* __restrict__ k,
                                              const float* __restrict__ v,
                                              _Float16* __restrict__ dst) {
  int Y = (int)blockIdx.y;
  size_t base = ((size_t)blockIdx.x * 256 + threadIdx.x) * 8;
  size_t b = base / (HG * 65536);
  size_t within = base - b * (HG * 65536);
  const float* src = (Y == 0 ? q : (Y == 1 ? k : v)) + b * 524288 + within;
  float4 a = ((const float4*)src)[0];
  float4 c = ((const float4*)src)[1];
  half8 h;
  h[0] = (_Float16)a.x; h[1] = (_Float16)a.y; h[2] = (_Float16)a.z; h[3] = (_Float16)a.w;
  h[4] = (_Float16)c.x; h[5] = (_Float16)c.y; h[6] = (_Float16)c.z; h[7] = (_Float16)c.w;
  *(half8*)(dst + (size_t)Y * HG * 524288 + base) = h;
}

// ---------------------------------------------------------------------------
template <int HG>
static void run_pipeline(const float* q_in, const float* k_in, const float* v_in,
                         const float* Wq, const float* Wk, const float* Wv,
                         const float* Wo, const float* bo, float* out, char* ws,
                         hipStream_t stream) {
  const int NG = 8 / HG;
  const long zc = 8 * HG;
  _Float16* W16 = (_Float16*)ws;                 // 8,388,608
  _Float16* in16 = W16 + 8388608;                // 3*HG*524288
  _Float16* Qp = in16 + 3L * HG * 524288;        // zc*524288 each
  _Float16* Kp = Qp + zc * 524288;
  _Float16* VWo = Kp + zc * 524288;
  _Float16* E = VWo + zc * 524288;               // zc*1048576
  _Float16* Vp = E;  // overlay: VWo dispatch (reads Vp) completes before
                     // energy dispatch (writes E) -- stream-ordered.
  _Float16* Wo16 = W16 + 3 * 2097152;
  dim3 blk(256);

  wbconv<<<dim3(8192), blk, 0, stream>>>(Wq, Wk, Wv, Wo, W16, out, bo);

  constexpr int HL = (HG >= 2) ? 2 : 1;
  constexpr int YS = HG / HL;

  for (int g = 0; g < NG; g++) {
    inconv<HG><<<dim3(HG * 256, 3), blk, 0, stream>>>(
        q_in + (size_t)g * HG * 65536, k_in + (size_t)g * HG * 65536,
        v_in + (size_t)g * HG * 65536, in16);

    proj256<HG><<<dim3(HG * 128, 3), blk, 0, stream>>>(in16, W16, Qp, Kp, Vp);

    vwo256<HG><<<dim3(16, HG, 8), blk, 0, stream>>>(
        Vp, Wo16 + (size_t)g * HG * 512, VWo);

    energy256<HG><<<dim3(20, HG, 8), blk, 0, stream>>>(Qp, Kp, E);

    softmax_rows<<<dim3(zc * 256), blk, 0, stream>>>(E);

    pv_kernel<HG, HL><<<dim3(32, YS, 8), blk, 0, stream>>>(E, VWo, out);
  }
}

extern "C" void kernel_launch(void* const* d_in, const int* in_sizes, int n_in,
                              void* d_out, int out_size, void* d_ws, size_t ws_size,
                              hipStream_t stream) {
  // setup_inputs order: k, v, q, mask, Wk, Wq, Wv, Wo, bo   (fp32)
  const float* k_in = (const float*)d_in[0];
  const float* v_in = (const float*)d_in[1];
  const float* q_in = (const float*)d_in[2];
  // d_in[3] = mask: exact causal tril, handled analytically
  const float* Wk = (const float*)d_in[4];
  const float* Wq = (const float*)d_in[5];
  const float* Wv = (const float*)d_in[6];
  const float* Wo = (const float*)d_in[7];
  const float* bo = (const float*)d_in[8];
  float* out = (float*)d_out;
  char* ws = (char*)d_ws;

  // exact footprints: HG=4 -> 197,132,288 B; HG=2 -> 106,954,752; HG=1 -> 61,865,984
  if (ws_size >= (size_t)197132288)
    run_pipeline<4>(q_in, k_in, v_in, Wq, Wk, Wv, Wo, bo, out, ws, stream);
  else if (ws_size >= (size_t)106954752)
    run_pipeline<2>(q_in, k_in, v_in, Wq, Wk, Wv, Wo, bo, out, ws, stream);
  else
    run_pipeline<1>(q_in, k_in, v_in, Wq, Wk, Wv, Wo, bo, out, ws, stream);
}

// Round 6
// 529.781 us; speedup vs baseline: 1.0579x; 1.0579x over previous
//
#include <hip/hip_runtime.h>

// MultiHead_Attn: B=8, S=1024, E=512, H=8.  fp32 I/O, fp16 MFMA internal.
//
// Reshape semantics (R3-verified): head (b,h) of (x@W^T).view(b,8,1024,512) is
// a CONTIGUOUS 1024x512 chunk of the natural row-major proj output.  Wo folded
// in early:  VWo_t[z][eo][s'] = Wo_h @ V_z^T,  out += P_z @ VWo_t_z^T.
// Group g = heads [g*HG,(g+1)*HG) of ALL 8 batches; in16 = [tensor][b][HG*128][512].
//
// R14 = R13 + T4 (counted vmcnt, the one untested lever):
//   - ring-3 LDS (3 x 24KB = 72KB/block, still 2 blocks/CU), stage(t+2) at t
//   - raw s_barrier + s_waitcnt vmcnt(6) at tile top: tile t's 6 glds retired,
//     tile t+1's stay IN FLIGHT across the barrier (never drain in loop).
//     R9-R13 all drained vmcnt(0)/tile (__syncthreads) -> ~900+cyc HBM+queue
//     latency exposed EVERY tile = the unexplained 2700cyc/tile gap.
//   - lgkmcnt(0) before tile-end: my reads of buf[t%3] retired before anyone
//     stages tile t+3 into it (WAR; issue happens after next top-barrier)
//   - unchanged: 128x256 4-wave core, 2 blocks/CU, paired-row XOR swizzle
//     (conflicts=0), static addressing, XCD-chunked proj swizzle
// pv (k-limited, atomic epilogue) kept on the 128^2 legacy core.
// VWo and energy remain SEPARATE dispatches: Vp is overlaid on E.
//
// Scratch (fp16 el): W16 8.39M | in16 3*HG*524288 | Qp,Kp,VWo zc*524288
// | E zc*1048576 (Vp overlay).  HG=4: 188 MiB, HG=2: 102 MiB, HG=1: 59 MiB.

typedef _Float16 half8 __attribute__((ext_vector_type(8)));
typedef _Float16 half4v __attribute__((ext_vector_type(4)));
typedef float f32x4 __attribute__((ext_vector_type(4)));

typedef __attribute__((address_space(3))) unsigned int lds_u32_t;
typedef __attribute__((address_space(1))) unsigned int g_u32_t;

__device__ __forceinline__ void glds16(const void* g, void* l) {
  // 16B/lane, LDS dest = wave-uniform base + lane*16  [m97: 517->874 TF]
  __builtin_amdgcn_global_load_lds((const g_u32_t*)g, (lds_u32_t*)l, 16, 0, 0);
}

// ========================= 128x256 4-wave core ==============================
// Tile M=128 (A rows) x N=256 (B rows) x BK=32.  Waves 2Mx2N, each 64x128
// (acc[4][8] = 128 VGPR).  LDS ring-3: buf = [A 4096 el][B 8192 el], 72KB.
// Paired-row layout (R11-verified conflict-free): LDS row' (128B) holds
// global rows {2r',2r'+1}; seg s' = ((g&1)*4 + c) ^ (r'&7); c = k-chunk(8el).
template <int NT>
__device__ __forceinline__ void gemm128x256_core(const _Float16* __restrict__ A,
                                                 const _Float16* __restrict__ B,
                                                 int lda, int ldb,
                                                 _Float16* smem, f32x4 (&acc)[4][8]) {
  int tid = (int)threadIdx.x;
  int w = tid >> 6, lane = tid & 63;
  int wr2 = (w >> 1) * 32;   // (wr = (w>>1)*64)/2  LDS-row base, A
  int wc2 = (w & 1) * 64;    // (wc = (w&1)*128)/2  LDS-row base, B
  int lr = lane & 15, hi = lane >> 4;
  // read swizzle: s' = ((g&1)*4 + hi) ^ (row'&7); g&1 = lane&1, row'&7=(lr>>1)&7
  int sp = ((((lane & 1) << 2) + hi) ^ ((lr >> 1) & 7)) << 3;  // elements
  int aBase = (wr2 + (lr >> 1)) * 64 + sp;
  int bBase = 4096 + (wc2 + (lr >> 1)) * 64 + sp;  // +4096 = B panel offset
  // B frags read via As[bBase + ...]: panel offset lives ONLY in bBase.

  // staging per-lane source offsets (elements); A: 2 glds, B: 4 glds
  int srcA[2], srcB[4], dstA[2], dstB[4];
#pragma unroll
  for (int e = 0; e < 2; e++) {
    int X = e * 4096 + tid * 16;        // dest byte in 8KB A panel
    int rp = X >> 7;
    int s = ((X >> 4) & 7) ^ (rp & 7);
    srcA[e] = (2 * rp + (s >> 2)) * lda + ((s & 3) << 3);
    dstA[e] = e * 2048 + w * 512;       // wave-uniform el (+ lane*16B by HW)
  }
#pragma unroll
  for (int e = 0; e < 4; e++) {
    int X = e * 4096 + tid * 16;        // dest byte in 16KB B panel
    int rp = X >> 7;
    int s = ((X >> 4) & 7) ^ (rp & 7);
    srcB[e] = (2 * rp + (s >> 2)) * ldb + ((s & 3) << 3);
    dstB[e] = 4096 + e * 2048 + w * 512;
  }

  // prologue: stage tile 0 -> buf0, tile 1 -> buf1 (12 glds outstanding)
#pragma unroll
  for (int e = 0; e < 2; e++) glds16(A + srcA[e], smem + dstA[e]);
#pragma unroll
  for (int e = 0; e < 4; e++) glds16(B + srcB[e], smem + dstB[e]);
  if (NT > 1) {
#pragma unroll
    for (int e = 0; e < 2; e++) glds16(A + srcA[e] + 32, smem + 12288 + dstA[e]);
#pragma unroll
    for (int e = 0; e < 4; e++) glds16(B + srcB[e] + 32, smem + 12288 + dstB[e]);
  }

#pragma unroll
  for (int t = 0; t < NT; t++) {
    // counted wait [T4]: retire tile t's 6 oldest glds; tile t+1's 6 stay in
    // flight across the barrier.  Barrier: all waves' tile-t stage visible AND
    // all waves' reads of buf[t%3] from tile t-3 retired (lgkm drain below).
    if (t + 1 < NT) asm volatile("s_waitcnt vmcnt(6)" ::: "memory");
    else            asm volatile("s_waitcnt vmcnt(0)" ::: "memory");
    __builtin_amdgcn_s_barrier();
    __builtin_amdgcn_sched_barrier(0);
    const _Float16* As = smem + (t % 3) * 12288;
    half8 a[4], b[4], c[4];
#pragma unroll
    for (int ni = 0; ni < 4; ni++) b[ni] = *(const half8*)&As[bBase + ni * 512];
#pragma unroll
    for (int mi = 0; mi < 4; mi++) a[mi] = *(const half8*)&As[aBase + mi * 512];
    if (t + 2 < NT) {
      _Float16* nb = smem + ((t + 2) % 3) * 12288;
#pragma unroll
      for (int e = 0; e < 2; e++) glds16(A + srcA[e] + (t + 2) * 32, nb + dstA[e]);
#pragma unroll
      for (int e = 0; e < 4; e++) glds16(B + srcB[e] + (t + 2) * 32, nb + dstB[e]);
    }
    __builtin_amdgcn_sched_barrier(0);  // pin group-1 reads + prefetch issue
#pragma unroll
    for (int ni = 0; ni < 4; ni++)
      c[ni] = *(const half8*)&As[bBase + (ni + 4) * 512];  // group-2 B frags
    __builtin_amdgcn_s_setprio(1);
    // compiler inserts fine lgkmcnt waits; group-2 reads overlap group-1 MFMA
#pragma unroll
    for (int mi = 0; mi < 4; mi++)
#pragma unroll
      for (int ni = 0; ni < 4; ni++)
        acc[mi][ni] = __builtin_amdgcn_mfma_f32_16x16x32_f16(a[mi], b[ni],
                                                             acc[mi][ni], 0, 0, 0);
#pragma unroll
    for (int mi = 0; mi < 4; mi++)
#pragma unroll
      for (int ni = 0; ni < 4; ni++)
        acc[mi][ni + 4] = __builtin_amdgcn_mfma_f32_16x16x32_f16(a[mi], c[ni],
                                                                 acc[mi][ni + 4], 0, 0, 0);
    __builtin_amdgcn_s_setprio(0);
    // all my ds_reads of buf[t%3] retired before I arrive at next barrier
    // (whoever stages tile t+3 into it issues AFTER that barrier)
    asm volatile("s_waitcnt lgkmcnt(0)" ::: "memory");
    __builtin_amdgcn_sched_barrier(0);
  }
  __syncthreads();  // all K-loop reads retired -> LDS free for epilogue reuse
}

// fp16 epilogue: per-wave private 64x64 LDS region x2 rounds (ni 0-3 / 4-7),
// XOR-swizzled segs, 16B coalesced stores.  Reuses staging LDS.
__device__ __forceinline__ void epilogue128x256(f32x4 (&acc)[4][8], _Float16* lds,
                                                _Float16* Cp, size_t cOff,
                                                int i0, int j0, int ldc) {
  int tid = (int)threadIdx.x;
  int w = tid >> 6, lane = tid & 63;
  int wr = (w >> 1) * 64, wc = (w & 1) * 128;
  int r0 = (lane >> 4) * 4, cl = lane & 15;
  _Float16* T = lds + w * 4096;
#pragma unroll
  for (int h = 0; h < 2; h++) {
#pragma unroll
    for (int mi = 0; mi < 4; mi++)
#pragma unroll
      for (int ni = 0; ni < 4; ni++) {
        int colb = ni * 16 + cl;
#pragma unroll
        for (int r = 0; r < 4; r++) {
          int row = mi * 16 + r0 + r;  // 0..63
          T[row * 64 + ((((colb >> 3) ^ row) & 7) << 3) + (colb & 7)] =
              (_Float16)acc[mi][h * 4 + ni][r];
        }
      }
    // wave-private region; same-wave LDS ops are in-order
#pragma unroll
    for (int st = 0; st < 8; st++) {
      int row = st * 8 + (lane >> 3);
      int c8 = lane & 7;
      half8 hh = *(const half8*)&T[row * 64 + (((c8 ^ row) & 7) << 3)];
      *(half8*)(Cp + cOff + (size_t)(i0 + wr + row) * ldc + j0 + wc + h * 64 + c8 * 8) = hh;
    }
  }
}

// ---- QKV projection: M=HG*1024, N=4096, K=512 ------------------------------
template <int HG>
__global__ __launch_bounds__(256, 2) void proj256(const _Float16* __restrict__ in16,
                                                  const _Float16* __restrict__ W16,
                                                  _Float16* __restrict__ Qp,
                                                  _Float16* __restrict__ Kp,
                                                  _Float16* __restrict__ Vp) {
  __shared__ __align__(16) _Float16 smem[36864];
  int x = (int)blockIdx.x, Y = (int)blockIdx.y;
  // XCD-chunked swizzle: grid.x = HG*128 (div by 8); XCD k gets contiguous
  // work chunk -> co-XCD blocks share A panels (L2 locality).
  int work = (x & 7) * (HG * 16) + (x >> 3);
  int it = work >> 4, jt = work & 15;
  const _Float16* A = in16 + (size_t)Y * HG * 524288 + (size_t)it * 65536;
  const _Float16* B = W16 + (size_t)Y * 2097152 + (size_t)jt * 131072;
  _Float16* C = (Y == 0 ? Qp : (Y == 1 ? Kp : Vp));
  f32x4 acc[4][8] = {};
  gemm128x256_core<16>(A, B, 512, 512, smem, acc);
  epilogue128x256(acc, smem, C, 0, it * 128, jt * 256, 4096);
}

// ---- VWo: VWo_t[z][eo][s'] = Wo_h @ V_z^T  (reads Vp = E overlay!) ---------
template <int HG>
__global__ __launch_bounds__(256, 2) void vwo256(const _Float16* __restrict__ Vp,
                                                 const _Float16* __restrict__ WoG,
                                                 _Float16* __restrict__ VWo) {
  __shared__ __align__(16) _Float16 smem[36864];
  int x = (int)blockIdx.x, Y = (int)blockIdx.y, Z = (int)blockIdx.z;
  size_t z = (size_t)Z * HG + Y;
  int i0 = (x >> 2) * 128, j0 = (x & 3) * 256;  // i0: eo-tile, j0: s'-tile
  const _Float16* A = WoG + (size_t)Y * 512 + (size_t)i0 * 4096;
  const _Float16* B = Vp + z * 524288 + (size_t)j0 * 512;
  f32x4 acc[4][8] = {};
  gemm128x256_core<16>(A, B, 4096, 512, smem, acc);
  epilogue128x256(acc, smem, VWo, z * 524288, i0, j0, 1024);
}

// ---- energy: E_z = Qp_z @ Kp_z^T, causal grid (20 of 32 tiles) -------------
template <int HG>
__global__ __launch_bounds__(256, 2) void energy256(const _Float16* __restrict__ Qp,
                                                    const _Float16* __restrict__ Kp,
                                                    _Float16* __restrict__ E) {
  __shared__ __align__(16) _Float16 smem[36864];
  int x = (int)blockIdx.x, Y = (int)blockIdx.y, Z = (int)blockIdx.z;
  size_t z = (size_t)Z * HG + Y;
  // tile (ti,tj) valid iff 2*tj <= ti: tj=0:ti0-7, 1:2-7, 2:4-7, 3:6-7
  int ti, tj;
  if (x < 8)       { tj = 0; ti = x; }
  else if (x < 14) { tj = 1; ti = x - 6; }
  else if (x < 18) { tj = 2; ti = x - 10; }
  else             { tj = 3; ti = x - 12; }
  int i0 = ti * 128, j0 = tj * 256;
  const _Float16* A = Qp + z * 524288 + (size_t)i0 * 512;
  const _Float16* B = Kp + z * 524288 + (size_t)j0 * 512;
  f32x4 acc[4][8] = {};
  gemm128x256_core<16>(A, B, 512, 512, smem, acc);
  epilogue128x256(acc, smem, E, z * 1048576, i0, j0, 1024);
}

// ===================== legacy 128^2 core (pv only) ==========================
template <int HL>
__device__ __forceinline__ void gemm_core(const _Float16* A, const _Float16* B,
                                          int lda, int ldb, int kmax,
                                          long sAh, long sBh,
                                          _Float16* As, _Float16* Bs,
                                          f32x4 (&acc)[4][4]) {
  int tid = (int)threadIdx.x;
  int w = tid >> 6, lane = tid & 63;
  int wr = (w >> 1) * 64, wc = (w & 1) * 64;
  int lr = lane & 15, lk = (lane >> 4) * 8;
  int srow = lane >> 2, sseg = (lane & 3) * 8;  // staging lane map

  for (int h = 0; h < HL; h++) {
    const _Float16* Ah = A + (size_t)h * sAh;
    const _Float16* Bh = B + (size_t)h * sBh;
    for (int k0 = 0; k0 < kmax; k0 += 64) {
      __syncthreads();  // previous iteration's frag reads complete
#pragma unroll
      for (int p = 0; p < 2; p++)
#pragma unroll
        for (int t = 0; t < 2; t++) {
          glds16(Ah + (size_t)(w * 32 + t * 16 + srow) * lda + k0 + p * 32 + sseg,
                 As + p * 4096 + (w * 32 + t * 16) * 32);
          glds16(Bh + (size_t)(w * 32 + t * 16 + srow) * ldb + k0 + p * 32 + sseg,
                 Bs + p * 4096 + (w * 32 + t * 16) * 32);
        }
      __syncthreads();  // vmcnt drained by barrier -> panels visible
#pragma unroll
      for (int p = 0; p < 2; p++) {
        half8 a[4], b[4];
#pragma unroll
        for (int mi = 0; mi < 4; mi++)
          a[mi] = *(half8*)&As[p * 4096 + (wr + mi * 16 + lr) * 32 + lk];
#pragma unroll
        for (int ni = 0; ni < 4; ni++)
          b[ni] = *(half8*)&Bs[p * 4096 + (wc + ni * 16 + lr) * 32 + lk];
#pragma unroll
        for (int mi = 0; mi < 4; mi++)
#pragma unroll
          for (int ni = 0; ni < 4; ni++)
            acc[mi][ni] =
                __builtin_amdgcn_mfma_f32_16x16x32_f16(a[mi], b[ni], acc[mi][ni], 0, 0, 0);
      }
    }
  }
}

// ---- atomic f32 epilogue (PV accumulation over heads) ----------------------
__device__ __forceinline__ void epilogue_atomic(f32x4 (&acc)[4][4], float* Cp,
                                                size_t cOff, int i0, int j0, int ldc) {
  int tid = (int)threadIdx.x;
  int w = tid >> 6, lane = tid & 63;
  int wr = (w >> 1) * 64, wc = (w & 1) * 64;
  int r0 = (lane >> 4) * 4, col = lane & 15;
#pragma unroll
  for (int mi = 0; mi < 4; mi++)
#pragma unroll
    for (int ni = 0; ni < 4; ni++)
#pragma unroll
      for (int r = 0; r < 4; r++)
        unsafeAtomicAdd(Cp + cOff + (size_t)(i0 + wr + mi * 16 + r0 + r) * ldc +
                            j0 + wc + ni * 16 + col,
                        acc[mi][ni][r]);
}

// ---- PV: out += P_z @ VWo_t_z^T (k-limited, HL heads in-register) ----------
template <int HG, int HL>
__global__ __launch_bounds__(256) void pv_kernel(const _Float16* __restrict__ E,
                                                 const _Float16* __restrict__ VWo,
                                                 float* __restrict__ out) {
  __shared__ __align__(16) _Float16 smem[17408];
  int x = (int)blockIdx.x, Y = (int)blockIdx.y, Z = (int)blockIdx.z;
  int i0 = (x >> 2) * 128, j0 = (x & 3) * 128;
  int kmax = i0 + 128;  // causal: P[q][s']==0 for s'>q
  const _Float16* A = E + ((size_t)Z * HG + (size_t)Y * HL) * 1048576 + (size_t)i0 * 1024;
  const _Float16* B = VWo + ((size_t)Z * HG + (size_t)Y * HL) * 524288 + (size_t)j0 * 1024;
  f32x4 acc[4][4] = {};
  gemm_core<HL>(A, B, 1024, 1024, kmax, 1048576, 524288, smem, smem + 8192, acc);
  epilogue_atomic(acc, out, (size_t)Z * 524288, i0, j0, 512);
}

// ---- row softmax, in-place E -> P (fp16), trimmed to valid 256-chunks ------
__global__ __launch_bounds__(256) void softmax_rows(void* __restrict__ Ep) {
  int R = (int)blockIdx.x * 4 + ((int)threadIdx.x >> 6);
  int lane = (int)threadIdx.x & 63;
  int i = R & 1023;
  int nt = (i >> 8) + 1;
  _Float16* row = (_Float16*)Ep + (size_t)R * 1024;
  float x[16];
  float m = -3.0e38f;
#pragma unroll
  for (int t = 0; t < 4; t++) {
    if (t < nt) {  // wave-uniform
      int j0 = t * 256 + lane * 4;
      half4v h = *(const half4v*)(row + j0);
#pragma unroll
      for (int c = 0; c < 4; c++) {
        float v = (j0 + c <= i) ? (float)h[c] * 0.125f : -3.0e38f;
        x[t * 4 + c] = v;
        m = fmaxf(m, v);
      }
    }
  }
#pragma unroll
  for (int s = 32; s > 0; s >>= 1) m = fmaxf(m, __shfl_xor(m, s, 64));
  float p[16];
  float sum = 0.0f;
#pragma unroll
  for (int t = 0; t < 4; t++) {
    if (t < nt) {
#pragma unroll
      for (int c = 0; c < 4; c++) {
        p[t * 4 + c] = exp2f((x[t * 4 + c] - m) * 1.44269504f);
        sum += p[t * 4 + c];
      }
    }
  }
#pragma unroll
  for (int s = 32; s > 0; s >>= 1) sum += __shfl_xor(sum, s, 64);
  float inv = 1.0f / sum;
#pragma unroll
  for (int t = 0; t < 4; t++) {
    if (t < nt) {
      int j0 = t * 256 + lane * 4;
      half4v h;
#pragma unroll
      for (int c = 0; c < 4; c++) h[c] = (_Float16)(p[t * 4 + c] * inv);
      *(half4v*)(row + j0) = h;
    }
  }
}

// ---- merged weight preconvert + bias init ----------------------------------
__global__ __launch_bounds__(256) void wbconv(const float* __restrict__ Wq,
                                              const float* __restrict__ Wk,
                                              const float* __restrict__ Wv,
                                              const float* __restrict__ Wo,
                                              _Float16* __restrict__ W16,
                                              float* __restrict__ out,
                                              const float* __restrict__ bo) {
  int bx = (int)blockIdx.x;
  if (bx < 4096) {
    size_t base = ((size_t)bx * 256 + threadIdx.x) * 8;
    int wid = (int)(base >> 21);
    size_t off = base & 2097151;
    const float* src = wid == 0 ? Wq : (wid == 1 ? Wk : (wid == 2 ? Wv : Wo));
    float4 a = *(const float4*)(src + off);
    float4 b = *(const float4*)(src + off + 4);
    half8 h;
    h[0] = (_Float16)a.x; h[1] = (_Float16)a.y; h[2] = (_Float16)a.z; h[3] = (_Float16)a.w;
    h[4] = (_Float16)b.x; h[5] = (_Float16)b.y; h[6] = (_Float16)b.z; h[7] = (_Float16)b.w;
    *(half8*)(W16 + base) = h;
  } else {
    size_t idx = ((size_t)(bx - 4096) * 256 + threadIdx.x) * 4;
    *(float4*)(out + idx) = *(const float4*)(bo + (idx & 511));
  }
}

// ---- input group-slice preconvert: in16[tensor][b][HG*128*512] fp16 --------
template <int HG>
__global__ __launch_bounds__(256) void inconv(const float* __restrict__ q,
                                              const float* __restrict__ k,
                                              const float* __restrict__ v,
                                              _Float16* __restrict__ dst) {
  int Y = (int)blockIdx.y;
  size_t base = ((size_t)blockIdx.x * 256 + threadIdx.x) * 8;
  size_t b = base / (HG * 65536);
  size_t within = base - b * (HG * 65536);
  const float* src = (Y == 0 ? q : (Y == 1 ? k : v)) + b * 524288 + within;
  float4 a = ((const float4*)src)[0];
  float4 c = ((const float4*)src)[1];
  half8 h;
  h[0] = (_Float16)a.x; h[1] = (_Float16)a.y; h[2] = (_Float16)a.z; h[3] = (_Float16)a.w;
  h[4] = (_Float16)c.x; h[5] = (_Float16)c.y; h[6] = (_Float16)c.z; h[7] = (_Float16)c.w;
  *(half8*)(dst + (size_t)Y * HG * 524288 + base) = h;
}

// ---------------------------------------------------------------------------
template <int HG>
static void run_pipeline(const float* q_in, const float* k_in, const float* v_in,
                         const float* Wq, const float* Wk, const float* Wv,
                         const float* Wo, const float* bo, float* out, char* ws,
                         hipStream_t stream) {
  const int NG = 8 / HG;
  const long zc = 8 * HG;
  _Float16* W16 = (_Float16*)ws;                 // 8,388,608
  _Float16* in16 = W16 + 8388608;                // 3*HG*524288
  _Float16* Qp = in16 + 3L * HG * 524288;        // zc*524288 each
  _Float16* Kp = Qp + zc * 524288;
  _Float16* VWo = Kp + zc * 524288;
  _Float16* E = VWo + zc * 524288;               // zc*1048576
  _Float16* Vp = E;  // overlay: VWo dispatch (reads Vp) completes before
                     // energy dispatch (writes E) -- stream-ordered.
  _Float16* Wo16 = W16 + 3 * 2097152;
  dim3 blk(256);

  wbconv<<<dim3(8192), blk, 0, stream>>>(Wq, Wk, Wv, Wo, W16, out, bo);

  constexpr int HL = (HG >= 2) ? 2 : 1;
  constexpr int YS = HG / HL;

  for (int g = 0; g < NG; g++) {
    inconv<HG><<<dim3(HG * 256, 3), blk, 0, stream>>>(
        q_in + (size_t)g * HG * 65536, k_in + (size_t)g * HG * 65536,
        v_in + (size_t)g * HG * 65536, in16);

    proj256<HG><<<dim3(HG * 128, 3), blk, 0, stream>>>(in16, W16, Qp, Kp, Vp);

    vwo256<HG><<<dim3(16, HG, 8), blk, 0, stream>>>(
        Vp, Wo16 + (size_t)g * HG * 512, VWo);

    energy256<HG><<<dim3(20, HG, 8), blk, 0, stream>>>(Qp, Kp, E);

    softmax_rows<<<dim3(zc * 256), blk, 0, stream>>>(E);

    pv_kernel<HG, HL><<<dim3(32, YS, 8), blk, 0, stream>>>(E, VWo, out);
  }
}

extern "C" void kernel_launch(void* const* d_in, const int* in_sizes, int n_in,
                              void* d_out, int out_size, void* d_ws, size_t ws_size,
                              hipStream_t stream) {
  // setup_inputs order: k, v, q, mask, Wk, Wq, Wv, Wo, bo   (fp32)
  const float* k_in = (const float*)d_in[0];
  const float* v_in = (const float*)d_in[1];
  const float* q_in = (const float*)d_in[2];
  // d_in[3] = mask: exact causal tril, handled analytically
  const float* Wk = (const float*)d_in[4];
  const float* Wq = (const float*)d_in[5];
  const float* Wv = (const float*)d_in[6];
  const float* Wo = (const float*)d_in[7];
  const float* bo = (const float*)d_in[8];
  float* out = (float*)d_out;
  char* ws = (char*)d_ws;

  // exact footprints: HG=4 -> 197,132,288 B; HG=2 -> 106,954,752; HG=1 -> 61,865,984
  if (ws_size >= (size_t)197132288)
    run_pipeline<4>(q_in, k_in, v_in, Wq, Wk, Wv, Wo, bo, out, ws, stream);
  else if (ws_size >= (size_t)106954752)
    run_pipeline<2>(q_in, k_in, v_in, Wq, Wk, Wv, Wo, bo, out, ws, stream);
  else
    run_pipeline<1>(q_in, k_in, v_in, Wq, Wk, Wv, Wo, bo, out, ws, stream);
}